// Round 2
// baseline (299.233 us; speedup 1.0000x reference)
//
#include <hip/hip_runtime.h>

// out = tile(v, 16) where v = x @ Wv^T + bv  (softmax over singleton axis == 1)
// x: [16384][2048] fp32, Wv = Wkv[128:256][:] fp32, bv = bkv[128:256]
// out: [16384][2048] fp32 (each row = 16 copies of the 128-wide v row)

typedef __attribute__((ext_vector_type(8))) short bf16x8;
typedef __attribute__((ext_vector_type(4))) float f32x4;

#define M_TOTAL 16384
#define K_DIM   2048
#define N_DIM   128
#define BM      16
#define BK      64
#define NT      (K_DIM / BK)   // 32
#define THREADS 256

__device__ __forceinline__ unsigned short f2bf(float f) {
    unsigned int u = __float_as_uint(f);
    u += 0x7FFFu + ((u >> 16) & 1u);   // RNE
    return (unsigned short)(u >> 16);
}

// Convert V-half of Wkv (rows 128..255, fp32) -> bf16 in workspace, row-major [128][2048].
__global__ void prep_wv(const float* __restrict__ Wkv, unsigned short* __restrict__ Wv) {
    int i = blockIdx.x * blockDim.x + threadIdx.x;           // 0 .. 65535 (x4 elems)
    const float4 f = reinterpret_cast<const float4*>(Wkv + N_DIM * K_DIM)[i];
    ushort4 o;
    o.x = f2bf(f.x); o.y = f2bf(f.y); o.z = f2bf(f.z); o.w = f2bf(f.w);
    reinterpret_cast<ushort4*>(Wv)[i] = o;
}

__global__ __launch_bounds__(THREADS) void mqa_v_gemm(
    const float* __restrict__ x,
    const unsigned short* __restrict__ Wv,
    const float* __restrict__ bkv,
    float* __restrict__ out)
{
    __shared__ __align__(16) unsigned short A_lds[2][BM * BK];  // bf16, XOR-swizzled, 2 KiB each
    __shared__ __align__(16) float v_lds[BM][132];              // +4 pad breaks write conflicts

    const int tid  = threadIdx.x;
    const int lane = tid & 63;
    const int wave = tid >> 6;                 // 0..3, owns cols [32w, 32w+32)
    const size_t row0 = (size_t)blockIdx.x * BM;

    // ---- A staging map: thread -> (row, 4 consecutive floats of k) ----
    const int srow = tid >> 4;                 // 0..15
    const int skc  = (tid & 15) << 2;          // k-float offset 0..60
    const float* xp = x + (row0 + srow) * K_DIM + skc;
    const int swz_byte = srow * 128 + (((skc << 1)) ^ ((srow & 7) << 4));

    // ---- MFMA fragment addressing ----
    const int frow = lane & 15;                // A row / B col / C col index
    const int fg   = lane >> 4;                // k-group 0..3
    const int a_byte0 = frow * 128 + (((fg << 4)      ) ^ ((frow & 7) << 4)); // k-sub 0
    const int a_byte1 = frow * 128 + (((fg << 4) | 64 ) ^ ((frow & 7) << 4)); // k-sub 1

    // B operand straight from L2: col = wave*32 + {0,16} + frow, k = k0 + s*32 + fg*8
    const unsigned short* wp0 = Wv + (wave * 32 +  0 + frow) * K_DIM + (fg << 3);
    const unsigned short* wp1 = Wv + (wave * 32 + 16 + frow) * K_DIM + (fg << 3);

    // ---- prologue: stage k-tile 0 ----
    float4 stg = *reinterpret_cast<const float4*>(xp);
    {
        ushort4 u = { f2bf(stg.x), f2bf(stg.y), f2bf(stg.z), f2bf(stg.w) };
        *reinterpret_cast<ushort4*>(reinterpret_cast<char*>(A_lds[0]) + swz_byte) = u;
    }
    __syncthreads();

    f32x4 acc0 = {0.f, 0.f, 0.f, 0.f};
    f32x4 acc1 = {0.f, 0.f, 0.f, 0.f};

    for (int t = 0; t < NT; ++t) {
        const int cur = t & 1;
        if (t + 1 < NT)                         // prefetch next A tile into regs
            stg = *reinterpret_cast<const float4*>(xp + (t + 1) * BK);

        const char* ab = reinterpret_cast<const char*>(A_lds[cur]);
        bf16x8 a0 = *reinterpret_cast<const bf16x8*>(ab + a_byte0);
        bf16x8 a1 = *reinterpret_cast<const bf16x8*>(ab + a_byte1);

        const int k0 = t * BK;
        bf16x8 b00 = *reinterpret_cast<const bf16x8*>(wp0 + k0);
        bf16x8 b10 = *reinterpret_cast<const bf16x8*>(wp1 + k0);
        bf16x8 b01 = *reinterpret_cast<const bf16x8*>(wp0 + k0 + 32);
        bf16x8 b11 = *reinterpret_cast<const bf16x8*>(wp1 + k0 + 32);

        acc0 = __builtin_amdgcn_mfma_f32_16x16x32_bf16(a0, b00, acc0, 0, 0, 0);
        acc1 = __builtin_amdgcn_mfma_f32_16x16x32_bf16(a0, b10, acc1, 0, 0, 0);
        acc0 = __builtin_amdgcn_mfma_f32_16x16x32_bf16(a1, b01, acc0, 0, 0, 0);
        acc1 = __builtin_amdgcn_mfma_f32_16x16x32_bf16(a1, b11, acc1, 0, 0, 0);

        if (t + 1 < NT) {                       // write next tile to other buffer
            ushort4 u = { f2bf(stg.x), f2bf(stg.y), f2bf(stg.z), f2bf(stg.w) };
            *reinterpret_cast<ushort4*>(reinterpret_cast<char*>(A_lds[cur ^ 1]) + swz_byte) = u;
        }
        __syncthreads();
    }

    // ---- epilogue: bias, stage v tile in LDS ----
    // C/D layout: col = lane&15, row = (lane>>4)*4 + j  [m89-verified]
    const int c0 = wave * 32 + frow;
    const int c1 = c0 + 16;
    const float bias0 = bkv[N_DIM + c0];
    const float bias1 = bkv[N_DIM + c1];
    #pragma unroll
    for (int j = 0; j < 4; ++j) {
        const int r = fg * 4 + j;
        v_lds[r][c0] = acc0[j] + bias0;
        v_lds[r][c1] = acc1[j] + bias1;
    }
    __syncthreads();

    // ---- replicated, fully-coalesced float4 output: each out row = 16 copies of v row ----
    float4* op = reinterpret_cast<float4*>(out + row0 * K_DIM);
    for (int i = tid; i < BM * (K_DIM / 4); i += THREADS) {
        const int r  = i >> 9;                  // 512 float4 per output row
        const int c4 = i & 31;                  // float4 index inside one 128-float copy
        op[i] = *reinterpret_cast<const float4*>(&v_lds[r][c4 << 2]);
    }
}

extern "C" void kernel_launch(void* const* d_in, const int* in_sizes, int n_in,
                              void* d_out, int out_size, void* d_ws, size_t ws_size,
                              hipStream_t stream)
{
    const float* x   = (const float*)d_in[0];
    // d_in[1] = Wq, d_in[2] = bq : dead code (softmax over singleton axis == 1)
    const float* Wkv = (const float*)d_in[3];
    const float* bkv = (const float*)d_in[4];
    float* out       = (float*)d_out;
    unsigned short* Wv = (unsigned short*)d_ws;   // 128*2048*2 = 512 KiB

    prep_wv<<<(N_DIM * K_DIM / 4) / 256, 256, 0, stream>>>(Wkv, Wv);
    mqa_v_gemm<<<M_TOTAL / BM, THREADS, 0, stream>>>(x, Wv, bkv, out);
}

// Round 3
// 266.272 us; speedup vs baseline: 1.1238x; 1.1238x over previous
//
#include <hip/hip_runtime.h>

// out = tile(v, 16) where v = x @ Wv^T + bv  (softmax over singleton axis == 1)
// x: [16384][2048] fp32, Wv = Wkv[128:256][:], bv = bkv[128:256]
// out[row][h*128+d] = v[row][d] for h=0..15 (fp32)
//
// Pipeline: per k-tile (BK=64) stage A (fp32, swizzled src) + B' (bf16,
// fragment-packed) into LDS via global_load_lds (16B), 4 buffers, 2 tiles in
// flight, counted vmcnt + raw s_barrier (m201 T3/T4 pattern).

typedef __attribute__((ext_vector_type(8))) short bf16x8;
typedef __attribute__((ext_vector_type(4))) float f32x4;

#define M_TOTAL 16384
#define K_DIM   2048
#define BM      16
#define BK      64
#define NT      (K_DIM / BK)      // 32
#define TILE_BYTES 20480          // A: 4 KiB fp32 + B': 16 KiB bf16
#define NBUF    4

__device__ __forceinline__ unsigned short f2bf(float f) {
    unsigned int u = __float_as_uint(f);
    u += 0x7FFFu + ((u >> 16) & 1u);   // RNE
    return (unsigned short)(u >> 16);
}

#define GLOAD_LDS16(gp, lp) __builtin_amdgcn_global_load_lds( \
    (const __attribute__((address_space(1))) void*)(gp),      \
    (__attribute__((address_space(3))) void*)(lp), 16, 0, 0)

#define WAITV(N) asm volatile("s_waitcnt vmcnt(" #N ")" ::: "memory")
#define BAR() do { asm volatile("" ::: "memory"); __builtin_amdgcn_s_barrier(); \
                   asm volatile("" ::: "memory"); } while (0)

// Pack V-half of Wkv into MFMA-fragment order, bf16:
// Wvp[t][cb][lane][8] with cb = ks*8 + c; element = Wv[c*16 + (lane&15)]
//                                                   [t*64 + ks*32 + (lane>>4)*8 + e]
__global__ void prep_wv(const float* __restrict__ Wkv, unsigned short* __restrict__ Wvp) {
    const int tid = blockIdx.x * 256 + threadIdx.x;   // 0..32767
    const int l  = tid & 63;
    const int cb = (tid >> 6) & 15;
    const int t  = tid >> 10;
    const int c  = cb & 7, ks = cb >> 3;
    const int col   = c * 16 + (l & 15);
    const int kbase = t * 64 + ks * 32 + (l >> 4) * 8;
    const float* src = Wkv + (size_t)(128 + col) * K_DIM + kbase;
    const float4 f0 = *reinterpret_cast<const float4*>(src);
    const float4 f1 = *reinterpret_cast<const float4*>(src + 4);
    ushort4 o0 = { f2bf(f0.x), f2bf(f0.y), f2bf(f0.z), f2bf(f0.w) };
    ushort4 o1 = { f2bf(f1.x), f2bf(f1.y), f2bf(f1.z), f2bf(f1.w) };
    ushort4* dst = reinterpret_cast<ushort4*>(Wvp + (size_t)tid * 8);
    dst[0] = o0; dst[1] = o1;
}

__global__ __launch_bounds__(256, 2) void mqa_v_gemm(
    const float* __restrict__ x,
    const unsigned short* __restrict__ Wvp,
    const float* __restrict__ bkv,
    float* __restrict__ out)
{
    __shared__ __align__(16) char smem[NBUF * TILE_BYTES];   // 80 KiB

    const int tid  = threadIdx.x;
    const int l    = tid & 63;
    const int w    = tid >> 6;            // 0..3, owns cols [32w, 32w+32)
    const int frow = l & 15;
    const int fg   = l >> 4;
    const size_t row0 = (size_t)blockIdx.x * BM;

    // ---- staging sources ----
    // A chunk (1 KiB per wave): DMA dest byte = w*1024 + l*16 -> (srow, c16=(l&15))
    // slot (row,c16) must hold x[row][4*(c16 ^ (row&7))] (inverse-swizzled source)
    const int srow   = w * 4 + (l >> 4);
    const int scol16 = frow ^ (srow & 7);
    const float* gA = x + (row0 + srow) * K_DIM + scol16 * 4;
    // B chunks: wave w stages cb = w, w+4, w+8, w+12 (each 1 KiB, linear)

    // ---- prologue: stage tiles 0,1 (5 loads per thread per tile) ----
    #define STAGE(t, buf) do {                                            \
        char* tb_ = smem + (buf) * TILE_BYTES;                            \
        GLOAD_LDS16(gA + (t) * BK, tb_ + w * 1024);                       \
        const unsigned short* gb_ = Wvp + (size_t)(t) * 8192 + w * 512 + l * 8; \
        GLOAD_LDS16(gb_,        tb_ + 4096 + (w     ) * 1024);            \
        GLOAD_LDS16(gb_ + 2048, tb_ + 4096 + (w +  4) * 1024);            \
        GLOAD_LDS16(gb_ + 4096, tb_ + 4096 + (w +  8) * 1024);            \
        GLOAD_LDS16(gb_ + 6144, tb_ + 4096 + (w + 12) * 1024);            \
    } while (0)

    f32x4 acc0 = {0.f, 0.f, 0.f, 0.f};
    f32x4 acc1 = {0.f, 0.f, 0.f, 0.f};

    #define COMPUTE(t) do {                                               \
        const char* tb_ = smem + ((t) & (NBUF - 1)) * TILE_BYTES;         \
        const char* Ab_ = tb_;                                            \
        const char* Bb_ = tb_ + 4096;                                     \
        _Pragma("unroll")                                                 \
        for (int ks = 0; ks < 2; ++ks) {                                  \
            float4 af0 = *reinterpret_cast<const float4*>(                \
                Ab_ + frow * 256 + (((ks * 8 + fg * 2 + 0) ^ (frow & 7)) << 4)); \
            float4 af1 = *reinterpret_cast<const float4*>(                \
                Ab_ + frow * 256 + (((ks * 8 + fg * 2 + 1) ^ (frow & 7)) << 4)); \
            union { unsigned int u[4]; bf16x8 v; } a_;                    \
            asm("v_cvt_pk_bf16_f32 %0, %1, %2" : "=v"(a_.u[0]) : "v"(af0.x), "v"(af0.y)); \
            asm("v_cvt_pk_bf16_f32 %0, %1, %2" : "=v"(a_.u[1]) : "v"(af0.z), "v"(af0.w)); \
            asm("v_cvt_pk_bf16_f32 %0, %1, %2" : "=v"(a_.u[2]) : "v"(af1.x), "v"(af1.y)); \
            asm("v_cvt_pk_bf16_f32 %0, %1, %2" : "=v"(a_.u[3]) : "v"(af1.z), "v"(af1.w)); \
            bf16x8 b0 = *reinterpret_cast<const bf16x8*>(                 \
                Bb_ + (ks * 8 + 2 * w    ) * 1024 + l * 16);              \
            bf16x8 b1 = *reinterpret_cast<const bf16x8*>(                 \
                Bb_ + (ks * 8 + 2 * w + 1) * 1024 + l * 16);              \
            acc0 = __builtin_amdgcn_mfma_f32_16x16x32_bf16(a_.v, b0, acc0, 0, 0, 0); \
            acc1 = __builtin_amdgcn_mfma_f32_16x16x32_bf16(a_.v, b1, acc1, 0, 0, 0); \
        }                                                                 \
    } while (0)

    STAGE(0, 0);
    STAGE(1, 1);

    // main loop: issue t+2, wait tile t (2 tiles * 5 loads in flight), barrier, compute
    for (int t = 0; t < NT - 2; ++t) {
        STAGE(t + 2, (t + 2) & (NBUF - 1));
        WAITV(10);
        BAR();
        COMPUTE(t);
    }
    WAITV(5);
    BAR();
    COMPUTE(NT - 2);
    WAITV(0);
    BAR();
    COMPUTE(NT - 1);

    // ---- epilogue: bias + v staged in LDS (aliases buf0; safe: all waves past
    // last barrier touch only bufs 1..3 regs) ----
    float* vl = reinterpret_cast<float*>(smem);           // [16][132], 8448 B
    const int c0 = w * 32 + frow;
    const int c1 = c0 + 16;
    const float bias0 = bkv[128 + c0];
    const float bias1 = bkv[128 + c1];
    #pragma unroll
    for (int j = 0; j < 4; ++j) {
        const int r = fg * 4 + j;
        vl[r * 132 + c0] = acc0[j] + bias0;
        vl[r * 132 + c1] = acc1[j] + bias1;
    }
    __syncthreads();   // loop is done; full drain is harmless here

    // replicated, fully-coalesced float4 output (each out row = 16 copies of v row)
    float4* op = reinterpret_cast<float4*>(out + row0 * K_DIM);
    #pragma unroll
    for (int i = tid; i < BM * (K_DIM / 4); i += 256) {
        const int r  = i >> 9;               // 512 float4 per output row
        const int c4 = i & 511;
        op[i] = *reinterpret_cast<const float4*>(vl + r * 132 + (c4 & 31) * 4);
    }
}

extern "C" void kernel_launch(void* const* d_in, const int* in_sizes, int n_in,
                              void* d_out, int out_size, void* d_ws, size_t ws_size,
                              hipStream_t stream)
{
    const float* x   = (const float*)d_in[0];
    // d_in[1] = Wq, d_in[2] = bq : dead (softmax over singleton axis == 1)
    const float* Wkv = (const float*)d_in[3];
    const float* bkv = (const float*)d_in[4];
    float* out       = (float*)d_out;
    unsigned short* Wvp = (unsigned short*)d_ws;   // 512 KiB fragment-packed bf16

    prep_wv<<<128, 256, 0, stream>>>(Wkv, Wvp);
    mqa_v_gemm<<<M_TOTAL / BM, 256, 0, stream>>>(x, Wvp, bkv, out);
}